// Round 1
// baseline (39319.873 us; speedup 1.0000x reference)
//
#include <hip/hip_runtime.h>

// LSTM: T=1024, B=64, IN=H=512.
// Persistent cooperative kernel: 2 batch-groups x 128 WGs. Each WG owns 4
// hidden units (16 gate rows) for 32 batches; c lives in LDS for the whole
// run; weights live in registers as MFMA B-fragments. Per-step inter-WG
// h exchange goes through d_out's h_seq region, gated by per-step flags in
// d_ws with release/acquire at agent scope (cross-XCD safe).

#define TT 1024
#define BB 64
#define DD 512
#define NBG 2
#define NWG 128
#define HU 4
#define BS 32

typedef _Float16 half8 __attribute__((ext_vector_type(8)));
typedef float f32x4 __attribute__((ext_vector_type(4)));

__device__ __forceinline__ float sigm(float v) { return 1.0f / (1.0f + __expf(-v)); }
__device__ __forceinline__ float tanh_fast(float v) { return 2.0f / (1.0f + __expf(-2.0f * v)) - 1.0f; }

__global__ __launch_bounds__(256) void lstm_persist(
    const float* __restrict__ x,
    const float* __restrict__ Wxf, const float* __restrict__ Whf,
    const float* __restrict__ Wxi, const float* __restrict__ Whi,
    const float* __restrict__ Wxo, const float* __restrict__ Who,
    const float* __restrict__ Wxg, const float* __restrict__ Whg,
    const float* __restrict__ bxf, const float* __restrict__ bhf,
    const float* __restrict__ bxi, const float* __restrict__ bhi,
    const float* __restrict__ bxo, const float* __restrict__ bho,
    const float* __restrict__ bxg, const float* __restrict__ bhg,
    float* __restrict__ out, int* __restrict__ flags)
{
    const int wg   = blockIdx.x;
    const int grp  = wg >> 7;        // batch group 0..1
    const int w    = wg & 127;       // unit-owner index 0..127
    const int tid  = threadIdx.x;
    const int wave = tid >> 6;       // 0,1: x-GEMM halves; 2,3: h-GEMM halves
    const int lane = tid & 63;
    const int quad = lane >> 4;
    const int l16  = lane & 15;

    __shared__ float zbuf[4][BS][16];   // per-wave partial z tiles
    __shared__ float c_lds[BS][HU];     // persistent cell state
    __shared__ float bias_lds[16];      // bx+bh for our 16 gate rows

    // ---- init: c=0, bias preload ----
    if (tid < 128) c_lds[tid >> 2][tid & 3] = 0.0f;
    if (tid < 16) {
        const int g = tid >> 2, u = tid & 3;
        const float* bx = (g == 0) ? bxf : (g == 1) ? bxi : (g == 2) ? bxo : bxg;
        const float* bh = (g == 0) ? bhf : (g == 1) ? bhi : (g == 2) ? bho : bhg;
        bias_lds[tid] = bx[w * HU + u] + bh[w * HU + u];
    }

    // ---- weight B-fragments into registers (once) ----
    // local gate-row n = l16:  gate = n>>2, unit = n&3; global row = gate*512 + w*4 + unit
    const int gate = l16 >> 2;
    const int u    = l16 & 3;
    const float* Wxsel = (gate == 0) ? Wxf : (gate == 1) ? Wxi : (gate == 2) ? Wxo : Wxg;
    const float* Whsel = (gate == 0) ? Whf : (gate == 1) ? Whi : (gate == 2) ? Who : Whg;
    const float* Wsel  = (wave < 2) ? Wxsel : Whsel;
    const int kq  = (wave & 1) << 8;       // this wave's K-quarter base (0 or 256)
    const int row = w * HU + u;
    half8 wfrag[8];
#pragma unroll
    for (int kc = 0; kc < 8; ++kc) {
        const float* p = Wsel + row * DD + kq + kc * 32 + quad * 8;
        half8 f;
#pragma unroll
        for (int j = 0; j < 8; ++j) f[j] = (_Float16)p[j];
        wfrag[kc] = f;
    }
    __syncthreads();

    const size_t hseq_sz = (size_t)TT * BB * DD;

    for (int t = 0; t < TT; ++t) {
        // ---- h-waves wait for producers of their k-slice (step t-1) ----
        if (wave >= 2 && t > 0) {
            int* fl = flags + ((grp * TT + (t - 1)) << 7) + ((wave - 2) << 6) + lane;
            while (__hip_atomic_load(fl, __ATOMIC_RELAXED, __HIP_MEMORY_SCOPE_AGENT) == 0)
                __builtin_amdgcn_s_sleep(1);
            __threadfence();   // acquire: invalidate stale L1/L2 before reading h
        }

        f32x4 acc0 = {0.f, 0.f, 0.f, 0.f};
        f32x4 acc1 = {0.f, 0.f, 0.f, 0.f};
        if (wave < 2 || t > 0) {
            const float* src = (wave < 2) ? (x + (size_t)t * BB * DD)
                                          : (out + (size_t)(t - 1) * BB * DD);
            const float* pa0 = src + (size_t)(grp * BS + l16) * DD + kq + quad * 8;
            const float* pa1 = pa0 + 16 * DD;
#pragma unroll
            for (int kc = 0; kc < 8; ++kc) {
                f32x4 a0lo = *(const f32x4*)(pa0 + kc * 32);
                f32x4 a0hi = *(const f32x4*)(pa0 + kc * 32 + 4);
                f32x4 a1lo = *(const f32x4*)(pa1 + kc * 32);
                f32x4 a1hi = *(const f32x4*)(pa1 + kc * 32 + 4);
                half8 a0, a1;
#pragma unroll
                for (int j = 0; j < 4; ++j) {
                    a0[j] = (_Float16)a0lo[j]; a0[4 + j] = (_Float16)a0hi[j];
                    a1[j] = (_Float16)a1lo[j]; a1[4 + j] = (_Float16)a1hi[j];
                }
                acc0 = __builtin_amdgcn_mfma_f32_16x16x32_f16(a0, wfrag[kc], acc0, 0, 0, 0);
                acc1 = __builtin_amdgcn_mfma_f32_16x16x32_f16(a1, wfrag[kc], acc1, 0, 0, 0);
            }
        }
        // D layout: value reg i of lane -> D[row = quad*4+i][col = l16]
#pragma unroll
        for (int i = 0; i < 4; ++i) {
            zbuf[wave][quad * 4 + i][l16]      = acc0[i];
            zbuf[wave][16 + quad * 4 + i][l16] = acc1[i];
        }
        __syncthreads();

        // ---- elementwise: 128 threads = 32 batches x 4 units ----
        if (tid < 128) {
            const int b = tid >> 2, uu = tid & 3;
            float zf = bias_lds[uu], zi = bias_lds[4 + uu], zo = bias_lds[8 + uu], zg = bias_lds[12 + uu];
#pragma unroll
            for (int wv = 0; wv < 4; ++wv) {
                zf += zbuf[wv][b][uu];
                zi += zbuf[wv][b][4 + uu];
                zo += zbuf[wv][b][8 + uu];
                zg += zbuf[wv][b][12 + uu];
            }
            float ff = sigm(zf), ig = sigm(zi), og = sigm(zo), gg = tanh_fast(zg);
            float c  = ff * c_lds[b][uu] + ig * gg;
            c_lds[b][uu] = c;
            float h  = og * tanh_fast(c);
            const size_t col = (size_t)(grp * BS + b) * DD + (w * HU + uu);
            out[(size_t)t * BB * DD + col] = h;
            if (t == TT - 1) out[hseq_sz + col] = h;   // final h output
        }
        __threadfence();      // release: push h stores to coherence point
        __syncthreads();
        if (tid == 0)
            __hip_atomic_store(flags + ((grp * TT + t) << 7) + w, 1,
                               __ATOMIC_RELEASE, __HIP_MEMORY_SCOPE_AGENT);
    }

    // ---- final c output ----
    if (tid < 128) {
        const int b = tid >> 2, uu = tid & 3;
        out[hseq_sz + BB * DD + (size_t)(grp * BS + b) * DD + (w * HU + uu)] = c_lds[b][uu];
    }
}

extern "C" void kernel_launch(void* const* d_in, const int* in_sizes, int n_in,
                              void* d_out, int out_size, void* d_ws, size_t ws_size,
                              hipStream_t stream) {
    const float* x   = (const float*)d_in[0];
    const float* Wxf = (const float*)d_in[1];  const float* bxf = (const float*)d_in[2];
    const float* Whf = (const float*)d_in[3];  const float* bhf = (const float*)d_in[4];
    const float* Wxi = (const float*)d_in[5];  const float* bxi = (const float*)d_in[6];
    const float* Whi = (const float*)d_in[7];  const float* bhi = (const float*)d_in[8];
    const float* Wxo = (const float*)d_in[9];  const float* bxo = (const float*)d_in[10];
    const float* Who = (const float*)d_in[11]; const float* bho = (const float*)d_in[12];
    const float* Wxg = (const float*)d_in[13]; const float* bxg = (const float*)d_in[14];
    const float* Whg = (const float*)d_in[15]; const float* bhg = (const float*)d_in[16];
    float* out = (float*)d_out;
    int* flags = (int*)d_ws;

    // flags are poisoned 0xAA before every timed launch -> zero them
    hipMemsetAsync(d_ws, 0, (size_t)NBG * TT * NWG * sizeof(int), stream);

    void* args[] = { &x,
                     &Wxf, &Whf, &Wxi, &Whi, &Wxo, &Who, &Wxg, &Whg,
                     &bxf, &bhf, &bxi, &bhi, &bxo, &bho, &bxg, &bhg,
                     &out, &flags };
    hipLaunchCooperativeKernel((const void*)lstm_persist,
                               dim3(NBG * NWG), dim3(256), args, 0, stream);
}

// Round 2
// 8593.027 us; speedup vs baseline: 4.5758x; 4.5758x over previous
//
#include <hip/hip_runtime.h>

// LSTM: T=1024, B=64, IN=H=512.
// Persistent cooperative kernel: 2 batch-groups x 128 WGs. Each WG owns 4
// hidden units (16 gate rows) for 32 batches; c lives in LDS; weights live in
// registers as MFMA B-fragments. Per-step h exchange goes through d_out's
// h_seq region using write-through (sc0 sc1) stores and cache-bypassing
// (sc0 sc1) loads -- coherent via the memory-side Infinity Cache, with NO
// L2-wide invalidate/writeback fences (round-0's 38us/step bottleneck).

#define TT 1024
#define BB 64
#define DD 512
#define NBG 2
#define NWG 128
#define HU 4
#define BS 32

typedef _Float16 half8 __attribute__((ext_vector_type(8)));
typedef float f32x4 __attribute__((ext_vector_type(4)));

__device__ __forceinline__ float sigm(float v) { return 1.0f / (1.0f + __expf(-v)); }
__device__ __forceinline__ float tanh_fast(float v) { return 2.0f / (1.0f + __expf(-2.0f * v)) - 1.0f; }

#define CVT8(DST, LO, HI) do { \
    DST[0] = (_Float16)LO[0]; DST[1] = (_Float16)LO[1]; \
    DST[2] = (_Float16)LO[2]; DST[3] = (_Float16)LO[3]; \
    DST[4] = (_Float16)HI[0]; DST[5] = (_Float16)HI[1]; \
    DST[6] = (_Float16)HI[2]; DST[7] = (_Float16)HI[3]; } while (0)

// 16 cache-bypassing dwordx4 loads (one 16x256-f32 A-slab row pair worth for
// this lane) batched behind a single vmcnt(0).
__device__ __forceinline__ void load_rows_coh(const float* p, half8 af[8]) {
    f32x4 r0, r1, r2, r3, r4, r5, r6, r7, r8, r9, r10, r11, r12, r13, r14, r15;
    asm volatile(
        "global_load_dwordx4 %0, %16, off sc0 sc1\n\t"
        "global_load_dwordx4 %1, %16, off offset:16 sc0 sc1\n\t"
        "global_load_dwordx4 %2, %16, off offset:128 sc0 sc1\n\t"
        "global_load_dwordx4 %3, %16, off offset:144 sc0 sc1\n\t"
        "global_load_dwordx4 %4, %16, off offset:256 sc0 sc1\n\t"
        "global_load_dwordx4 %5, %16, off offset:272 sc0 sc1\n\t"
        "global_load_dwordx4 %6, %16, off offset:384 sc0 sc1\n\t"
        "global_load_dwordx4 %7, %16, off offset:400 sc0 sc1\n\t"
        "global_load_dwordx4 %8, %16, off offset:512 sc0 sc1\n\t"
        "global_load_dwordx4 %9, %16, off offset:528 sc0 sc1\n\t"
        "global_load_dwordx4 %10, %16, off offset:640 sc0 sc1\n\t"
        "global_load_dwordx4 %11, %16, off offset:656 sc0 sc1\n\t"
        "global_load_dwordx4 %12, %16, off offset:768 sc0 sc1\n\t"
        "global_load_dwordx4 %13, %16, off offset:784 sc0 sc1\n\t"
        "global_load_dwordx4 %14, %16, off offset:896 sc0 sc1\n\t"
        "global_load_dwordx4 %15, %16, off offset:912 sc0 sc1\n\t"
        "s_waitcnt vmcnt(0)"
        : "=v"(r0), "=v"(r1), "=v"(r2), "=v"(r3), "=v"(r4), "=v"(r5), "=v"(r6), "=v"(r7),
          "=v"(r8), "=v"(r9), "=v"(r10), "=v"(r11), "=v"(r12), "=v"(r13), "=v"(r14), "=v"(r15)
        : "v"(p)
        : "memory");
    CVT8(af[0], r0, r1);   CVT8(af[1], r2, r3);
    CVT8(af[2], r4, r5);   CVT8(af[3], r6, r7);
    CVT8(af[4], r8, r9);   CVT8(af[5], r10, r11);
    CVT8(af[6], r12, r13); CVT8(af[7], r14, r15);
}

__global__ __launch_bounds__(256) void lstm_persist(
    const float* __restrict__ x,
    const float* __restrict__ Wxf, const float* __restrict__ Whf,
    const float* __restrict__ Wxi, const float* __restrict__ Whi,
    const float* __restrict__ Wxo, const float* __restrict__ Who,
    const float* __restrict__ Wxg, const float* __restrict__ Whg,
    const float* __restrict__ bxf, const float* __restrict__ bhf,
    const float* __restrict__ bxi, const float* __restrict__ bhi,
    const float* __restrict__ bxo, const float* __restrict__ bho,
    const float* __restrict__ bxg, const float* __restrict__ bhg,
    float* __restrict__ out, int* __restrict__ flags)
{
    const int wg   = blockIdx.x;
    const int grp  = wg >> 7;        // batch group 0..1
    const int w    = wg & 127;       // unit-owner index 0..127
    const int tid  = threadIdx.x;
    const int wave = tid >> 6;       // 0,1: x-GEMM halves; 2,3: h-GEMM halves
    const int lane = tid & 63;
    const int quad = lane >> 4;
    const int l16  = lane & 15;

    __shared__ float zbuf[4][BS][17];   // padded: kills LDS bank conflicts
    __shared__ float c_lds[BS][HU];     // persistent cell state
    __shared__ float bias_lds[16];      // bx+bh for our 16 gate rows

    if (tid < 128) c_lds[tid >> 2][tid & 3] = 0.0f;
    if (tid < 16) {
        const int g = tid >> 2, u = tid & 3;
        const float* bx = (g == 0) ? bxf : (g == 1) ? bxi : (g == 2) ? bxo : bxg;
        const float* bh = (g == 0) ? bhf : (g == 1) ? bhi : (g == 2) ? bho : bhg;
        bias_lds[tid] = bx[w * HU + u] + bh[w * HU + u];
    }

    // ---- weight B-fragments into registers (once) ----
    const int gate = l16 >> 2;
    const int u    = l16 & 3;
    const float* Wxsel = (gate == 0) ? Wxf : (gate == 1) ? Wxi : (gate == 2) ? Wxo : Wxg;
    const float* Whsel = (gate == 0) ? Whf : (gate == 1) ? Whi : (gate == 2) ? Who : Whg;
    const float* Wsel  = (wave < 2) ? Wxsel : Whsel;
    const int kq  = (wave & 1) << 8;       // this wave's K-quarter base (0 or 256)
    const int row = w * HU + u;
    half8 wfrag[8];
#pragma unroll
    for (int kc = 0; kc < 8; ++kc) {
        const float* p = Wsel + row * DD + kq + kc * 32 + quad * 8;
        half8 f;
#pragma unroll
        for (int j = 0; j < 8; ++j) f[j] = (_Float16)p[j];
        wfrag[kc] = f;
    }
    __syncthreads();

    const size_t hseq_sz = (size_t)TT * BB * DD;

    for (int t = 0; t < TT; ++t) {
        f32x4 acc0 = {0.f, 0.f, 0.f, 0.f};
        f32x4 acc1 = {0.f, 0.f, 0.f, 0.f};

        if (wave < 2) {
            // x-projection: normal cached loads (L2-resident now; no invalidates)
            const float* src = x + (size_t)t * BB * DD;
            const float* pa0 = src + (size_t)(grp * BS + l16) * DD + kq + quad * 8;
            const float* pa1 = pa0 + 16 * DD;
#pragma unroll
            for (int kc = 0; kc < 8; ++kc) {
                f32x4 a0lo = *(const f32x4*)(pa0 + kc * 32);
                f32x4 a0hi = *(const f32x4*)(pa0 + kc * 32 + 4);
                f32x4 a1lo = *(const f32x4*)(pa1 + kc * 32);
                f32x4 a1hi = *(const f32x4*)(pa1 + kc * 32 + 4);
                half8 a0, a1;
                CVT8(a0, a0lo, a0hi);
                CVT8(a1, a1lo, a1hi);
                acc0 = __builtin_amdgcn_mfma_f32_16x16x32_f16(a0, wfrag[kc], acc0, 0, 0, 0);
                acc1 = __builtin_amdgcn_mfma_f32_16x16x32_f16(a1, wfrag[kc], acc1, 0, 0, 0);
            }
        } else if (t > 0) {
            // wait for the 64 producers of this wave's k-slice (step t-1)
            const int* fl = flags + ((grp * TT + (t - 1)) << 7) + ((wave - 2) << 6) + lane;
            int f;
            asm volatile("global_load_dword %0, %1, off sc0 sc1\n\ts_waitcnt vmcnt(0)"
                         : "=v"(f) : "v"(fl) : "memory");
            while (f == 0) {
                __builtin_amdgcn_s_sleep(1);
                asm volatile("global_load_dword %0, %1, off sc0 sc1\n\ts_waitcnt vmcnt(0)"
                             : "=v"(f) : "v"(fl) : "memory");
            }
            // h-projection: cache-bypassing loads straight from LLC
            const float* src = out + (size_t)(t - 1) * BB * DD;
            const float* pa0 = src + (size_t)(grp * BS + l16) * DD + kq + quad * 8;
            half8 af[8];
            load_rows_coh(pa0, af);
#pragma unroll
            for (int kc = 0; kc < 8; ++kc)
                acc0 = __builtin_amdgcn_mfma_f32_16x16x32_f16(af[kc], wfrag[kc], acc0, 0, 0, 0);
            load_rows_coh(pa0 + 16 * DD, af);
#pragma unroll
            for (int kc = 0; kc < 8; ++kc)
                acc1 = __builtin_amdgcn_mfma_f32_16x16x32_f16(af[kc], wfrag[kc], acc1, 0, 0, 0);
        }

        // D layout: value reg i of lane -> D[row = quad*4+i][col = l16]
#pragma unroll
        for (int i = 0; i < 4; ++i) {
            zbuf[wave][quad * 4 + i][l16]      = acc0[i];
            zbuf[wave][16 + quad * 4 + i][l16] = acc1[i];
        }
        __syncthreads();

        // ---- elementwise: 128 threads = 32 batches x 4 units ----
        if (tid < 128) {
            const int b = tid >> 2, uu = tid & 3;
            float zf = bias_lds[uu], zi = bias_lds[4 + uu], zo = bias_lds[8 + uu], zg = bias_lds[12 + uu];
#pragma unroll
            for (int wv = 0; wv < 4; ++wv) {
                zf += zbuf[wv][b][uu];
                zi += zbuf[wv][b][4 + uu];
                zo += zbuf[wv][b][8 + uu];
                zg += zbuf[wv][b][12 + uu];
            }
            float ff = sigm(zf), ig = sigm(zi), og = sigm(zo), gg = tanh_fast(zg);
            float c  = ff * c_lds[b][uu] + ig * gg;
            c_lds[b][uu] = c;
            float h  = og * tanh_fast(c);
            const size_t col = (size_t)(grp * BS + b) * DD + (w * HU + uu);
            float* hp = out + (size_t)t * BB * DD + col;
            // write-through so consumers' bypassing loads see it at the LLC
            asm volatile("global_store_dword %0, %1, off sc0 sc1"
                         :: "v"(hp), "v"(h) : "memory");
            if (t == TT - 1) out[hseq_sz + col] = h;   // final h output
        }
        // release ordering without buffer_wbl2: drain own write-through stores
        asm volatile("s_waitcnt vmcnt(0)" ::: "memory");
        __syncthreads();
        if (tid == 0) {
            int one = 1;
            int* fp = flags + ((grp * TT + t) << 7) + w;
            asm volatile("global_store_dword %0, %1, off sc0 sc1"
                         :: "v"(fp), "v"(one) : "memory");
        }
    }

    // ---- final c output ----
    if (tid < 128) {
        const int b = tid >> 2, uu = tid & 3;
        out[hseq_sz + BB * DD + (size_t)(grp * BS + b) * DD + (w * HU + uu)] = c_lds[b][uu];
    }
}

extern "C" void kernel_launch(void* const* d_in, const int* in_sizes, int n_in,
                              void* d_out, int out_size, void* d_ws, size_t ws_size,
                              hipStream_t stream) {
    const float* x   = (const float*)d_in[0];
    const float* Wxf = (const float*)d_in[1];  const float* bxf = (const float*)d_in[2];
    const float* Whf = (const float*)d_in[3];  const float* bhf = (const float*)d_in[4];
    const float* Wxi = (const float*)d_in[5];  const float* bxi = (const float*)d_in[6];
    const float* Whi = (const float*)d_in[7];  const float* bhi = (const float*)d_in[8];
    const float* Wxo = (const float*)d_in[9];  const float* bxo = (const float*)d_in[10];
    const float* Who = (const float*)d_in[11]; const float* bho = (const float*)d_in[12];
    const float* Wxg = (const float*)d_in[13]; const float* bxg = (const float*)d_in[14];
    const float* Whg = (const float*)d_in[15]; const float* bhg = (const float*)d_in[16];
    float* out = (float*)d_out;
    int* flags = (int*)d_ws;

    // flags are poisoned 0xAA before every timed launch -> zero them
    hipMemsetAsync(d_ws, 0, (size_t)NBG * TT * NWG * sizeof(int), stream);

    void* args[] = { &x,
                     &Wxf, &Whf, &Wxi, &Whi, &Wxo, &Who, &Wxg, &Whg,
                     &bxf, &bhf, &bxi, &bhi, &bxo, &bho, &bxg, &bhg,
                     &out, &flags };
    hipLaunchCooperativeKernel((const void*)lstm_persist,
                               dim3(NBG * NWG), dim3(256), args, 0, stream);
}